// Round 1
// baseline (308.999 us; speedup 1.0000x reference)
//
#include <hip/hip_runtime.h>
#include <hip/hip_bf16.h>

#define B_SZ 16384
#define I_SZ 256
#define H_SZ 256
#define S_SZ 32

typedef __attribute__((ext_vector_type(8))) short short8;
typedef __attribute__((ext_vector_type(4))) float f32x4;
typedef __attribute__((ext_vector_type(4))) short s16x4;

__device__ __forceinline__ ushort f2b(float f) {
  __hip_bfloat16 h = __float2bfloat16(f);
  return *reinterpret_cast<ushort*>(&h);
}
__device__ __forceinline__ float b2f(ushort u) {
  unsigned x = ((unsigned)u) << 16;
  float f;
  __builtin_memcpy(&f, &x, 4);
  return f;
}
__device__ __forceinline__ float sgm(float x) { return 1.0f / (1.0f + expf(-x)); }

__device__ __forceinline__ void gll16(const void* g, void* l) {
  __builtin_amdgcn_global_load_lds(
      (const __attribute__((address_space(1))) unsigned*)g,
      (__attribute__((address_space(3))) unsigned*)l, 16, 0, 0);
}

// ---------------- prep: convert + transpose weights to bf16 ----------------
// WspT[n][k] = W_sp[k][n]   (256 x 256)
// WcatT[n][k] = k<512 ? W_ih[k][n] : W_hh[k-512][n]   (1024 x 768)
__global__ __launch_bounds__(256) void prep_weights(
    const float* __restrict__ W_sp, const float* __restrict__ W_ih,
    const float* __restrict__ W_hh, ushort* __restrict__ WspT,
    ushort* __restrict__ WcatT) {
  int idx = blockIdx.x * 256 + threadIdx.x;
  if (idx < 256 * 256) {
    int n = idx >> 8, k = idx & 255;
    WspT[idx] = f2b(W_sp[k * 256 + n]);
  } else {
    int j = idx - 256 * 256;  // < 1024*768
    int n = j / 768, k = j - n * 768;
    float v = (k < 512) ? W_ih[k * 1024 + n] : W_hh[(k - 512) * 1024 + n];
    WcatT[j] = f2b(v);
  }
}

// ---------------- fused event gate + scatter-copy + pooled ----------------
// One wave per batch row. 256 threads = 4 rows/block.
__global__ __launch_bounds__(256) void event_pool(
    const float* __restrict__ x_t, const float* __restrict__ h_lstm,
    const float* __restrict__ slots, const int* __restrict__ ptr,
    const float* __restrict__ W_val, const float* __restrict__ b_val,
    const float* __restrict__ W_ev, const float* __restrict__ b_ev,
    const float* __restrict__ pos_emb, const float* __restrict__ slot_w,
    float* __restrict__ out_slots, float* __restrict__ out_ptr,
    ushort* __restrict__ x_b, ushort* __restrict__ hl_b,
    ushort* __restrict__ pooled_b) {
  int l = threadIdx.x & 63;
  int w = threadIdx.x >> 6;
  int b = blockIdx.x * 4 + w;
  __shared__ float x_sh[4][256];

  float4 x4 = *(const float4*)(x_t + (size_t)b * 256 + l * 4);
  *(float4*)&x_sh[w][l * 4] = x4;
  ushort4 xb = make_ushort4(f2b(x4.x), f2b(x4.y), f2b(x4.z), f2b(x4.w));
  *(ushort4*)&x_b[(size_t)b * 256 + l * 4] = xb;
  float4 hl4 = *(const float4*)(h_lstm + (size_t)b * 256 + l * 4);
  ushort4 hb = make_ushort4(f2b(hl4.x), f2b(hl4.y), f2b(hl4.z), f2b(hl4.w));
  *(ushort4*)&hl_b[(size_t)b * 256 + l * 4] = hb;

  // event gate: z = dot(x, W_ev) + b_ev  (fp32, wave butterfly reduce)
  float4 we4 = *(const float4*)(W_ev + l * 4);
  float p = x4.x * we4.x + x4.y * we4.y + x4.z * we4.z + x4.w * we4.w;
  for (int off = 32; off; off >>= 1) p += __shfl_xor(p, off, 64);
  float z = p + b_ev[0];
  bool ev = sgm(z) > 0.85f;
  int pb = ptr[b];

  __syncthreads();  // x_sh ready

  // v = x @ W_val + b_val  (fp32) — only when the (rare) event fires
  float4 v4 = make_float4(0.f, 0.f, 0.f, 0.f);
  if (ev) {
    v4 = *(const float4*)(b_val + l * 4);
    for (int k = 0; k < 256; k++) {
      float xv = x_sh[w][k];
      float4 wv = *(const float4*)(W_val + (size_t)k * 256 + l * 4);
      v4.x += xv * wv.x; v4.y += xv * wv.y;
      v4.z += xv * wv.z; v4.w += xv * wv.w;
    }
  }

  // softmax(slot_weights) — tiny, computed redundantly per lane
  float mx = -1e30f;
  for (int s = 0; s < 32; s++) mx = fmaxf(mx, slot_w[s]);
  float sum = 0.f;
  for (int s = 0; s < 32; s++) sum += expf(slot_w[s] - mx);
  float rs = 1.f / sum;

  // single pass: copy slots -> out (with scatter), accumulate pooled
  const float4* sl4 = (const float4*)slots + (size_t)b * 2048;
  float4* os4 = (float4*)out_slots + (size_t)b * 2048;
  const float4* pe4 = (const float4*)pos_emb;
  float4 pool = make_float4(0.f, 0.f, 0.f, 0.f);
#pragma unroll 8
  for (int s = 0; s < 32; s++) {
    float ws_ = expf(slot_w[s] - mx) * rs;
    float4 t = sl4[s * 64 + l];
    if (ev && s == pb) t = v4;
    os4[s * 64 + l] = t;
    float4 pe = pe4[s * 64 + l];
    pool.x += ws_ * (t.x + pe.x);
    pool.y += ws_ * (t.y + pe.y);
    pool.z += ws_ * (t.z + pe.z);
    pool.w += ws_ * (t.w + pe.w);
  }
  ushort4 pb4 = make_ushort4(f2b(pool.x), f2b(pool.y), f2b(pool.z), f2b(pool.w));
  *(ushort4*)&pooled_b[(size_t)b * 256 + l * 4] = pb4;

  if (l == 0) out_ptr[b] = (float)(ev ? ((pb + 1) & 31) : pb);
}

// ---------------- bf16 MFMA GEMM: C = A(MxK) * W^T(NxK) + bias ----------------
// A split over up to 3 row-major (x,256) bf16 sources along K (256 each).
// EPI 0: write fp32 out + bf16 copy (h_mem).  EPI 1: write bf16 gates.
template <int KTOT, int NTOT, int EPI>
__global__ __launch_bounds__(256) void gemm_bf16(
    const ushort* __restrict__ A0, const ushort* __restrict__ A1,
    const ushort* __restrict__ A2, const ushort* __restrict__ WT,
    const float* __restrict__ bias, float* __restrict__ out_f32,
    ushort* __restrict__ out_b16) {
  int l = threadIdx.x & 63;
  int wid = threadIdx.x >> 6;
  int wm = wid >> 1, wn = wid & 1;
  int m0 = blockIdx.x * 128;
  int n0 = blockIdx.y * 128;
  __shared__ ushort Ash[128 * 32];
  __shared__ ushort Bsh[128 * 32];

  f32x4 acc[4][4] = {};

  for (int k0 = 0; k0 < KTOT; k0 += 32) {
    const ushort* As = (k0 < 256) ? A0 : ((k0 < 512) ? A1 : A2);
    int kc = k0 & 255;
#pragma unroll
    for (int i = 0; i < 2; i++) {
      int seg = i * 256 + threadIdx.x;
      int row = seg >> 2, cb = (seg & 3) * 8;
      gll16(As + (size_t)(m0 + row) * 256 + kc + cb, Ash + seg * 8);
    }
#pragma unroll
    for (int i = 0; i < 2; i++) {
      int seg = i * 256 + threadIdx.x;
      int row = seg >> 2, cb = (seg & 3) * 8;
      gll16(WT + (size_t)(n0 + row) * KTOT + k0 + cb, Bsh + seg * 8);
    }
    __syncthreads();

    short8 af[4], bfr[4];
#pragma unroll
    for (int m = 0; m < 4; m++)
      af[m] = *(const short8*)&Ash[(wm * 64 + m * 16 + (l & 15)) * 32 + (l >> 4) * 8];
#pragma unroll
    for (int n = 0; n < 4; n++)
      bfr[n] = *(const short8*)&Bsh[(wn * 64 + n * 16 + (l & 15)) * 32 + (l >> 4) * 8];
#pragma unroll
    for (int m = 0; m < 4; m++)
#pragma unroll
      for (int n = 0; n < 4; n++)
        acc[m][n] = __builtin_amdgcn_mfma_f32_16x16x32_bf16(af[m], bfr[n], acc[m][n], 0, 0, 0);
    __syncthreads();
  }

#pragma unroll
  for (int m = 0; m < 4; m++)
#pragma unroll
    for (int n = 0; n < 4; n++)
#pragma unroll
      for (int r = 0; r < 4; r++) {
        int row = m0 + wm * 64 + m * 16 + (l >> 4) * 4 + r;
        int col = n0 + wn * 64 + n * 16 + (l & 15);
        float v = acc[m][n][r] + bias[col];
        if constexpr (EPI == 0) {
          out_f32[(size_t)row * NTOT + col] = v;
          out_b16[(size_t)row * NTOT + col] = f2b(v);
        } else {
          out_b16[(size_t)row * NTOT + col] = f2b(v);
        }
      }
}

// ---------------- elementwise LSTM ----------------
__global__ __launch_bounds__(256) void lstm_ew(
    const ushort* __restrict__ gates, const float* __restrict__ c_lstm,
    float* __restrict__ h_out, float* __restrict__ c_out) {
  int t = blockIdx.x * 256 + threadIdx.x;  // 0 .. B*H/4
  int b = t >> 6;
  int h4 = (t & 63) * 4;
  size_t g0 = (size_t)b * 1024 + h4;
  s16x4 ig = *(const s16x4*)&gates[g0];
  s16x4 fg = *(const s16x4*)&gates[g0 + 256];
  s16x4 gg = *(const s16x4*)&gates[g0 + 512];
  s16x4 og = *(const s16x4*)&gates[g0 + 768];
  float4 c = *(const float4*)&c_lstm[(size_t)b * 256 + h4];
  float4 cn, hn;
  {
    float i0 = sgm(b2f((ushort)ig[0])), f0 = sgm(b2f((ushort)fg[0]));
    float g0v = tanhf(b2f((ushort)gg[0])), o0 = sgm(b2f((ushort)og[0]));
    cn.x = f0 * c.x + i0 * g0v; hn.x = o0 * tanhf(cn.x);
  }
  {
    float i1 = sgm(b2f((ushort)ig[1])), f1 = sgm(b2f((ushort)fg[1]));
    float g1 = tanhf(b2f((ushort)gg[1])), o1 = sgm(b2f((ushort)og[1]));
    cn.y = f1 * c.y + i1 * g1; hn.y = o1 * tanhf(cn.y);
  }
  {
    float i2 = sgm(b2f((ushort)ig[2])), f2 = sgm(b2f((ushort)fg[2]));
    float g2 = tanhf(b2f((ushort)gg[2])), o2 = sgm(b2f((ushort)og[2]));
    cn.z = f2 * c.z + i2 * g2; hn.z = o2 * tanhf(cn.z);
  }
  {
    float i3 = sgm(b2f((ushort)ig[3])), f3 = sgm(b2f((ushort)fg[3]));
    float g3 = tanhf(b2f((ushort)gg[3])), o3 = sgm(b2f((ushort)og[3]));
    cn.w = f3 * c.w + i3 * g3; hn.w = o3 * tanhf(cn.w);
  }
  size_t o = (size_t)b * 256 + h4;
  *(float4*)&c_out[o] = cn;
  *(float4*)&h_out[o] = hn;
}

extern "C" void kernel_launch(void* const* d_in, const int* in_sizes, int n_in,
                              void* d_out, int out_size, void* d_ws, size_t ws_size,
                              hipStream_t stream) {
  const float* x_t    = (const float*)d_in[0];
  const float* h_lstm = (const float*)d_in[1];
  const float* c_lstm = (const float*)d_in[2];
  // d_in[3] = h_mem_prev (unused by reference)
  const float* slots  = (const float*)d_in[4];
  const int*   ptr    = (const int*)d_in[5];
  const float* W_val  = (const float*)d_in[6];
  const float* b_val  = (const float*)d_in[7];
  const float* W_ev   = (const float*)d_in[8];
  const float* b_ev   = (const float*)d_in[9];
  const float* pos_emb = (const float*)d_in[10];
  const float* slot_w  = (const float*)d_in[11];
  const float* W_sp   = (const float*)d_in[12];
  const float* b_sp   = (const float*)d_in[13];
  const float* W_ih   = (const float*)d_in[14];
  const float* b_ih   = (const float*)d_in[15];
  const float* W_hh   = (const float*)d_in[16];

  float* out = (float*)d_out;
  const size_t BH = (size_t)B_SZ * H_SZ;              // 4,194,304
  float* out_h    = out;
  float* out_c    = out + BH;
  float* out_hmem = out + 2 * BH;
  float* out_slots = out + 3 * BH;
  float* out_ptr   = out + 3 * BH + (size_t)B_SZ * S_SZ * I_SZ;

  char* ws = (char*)d_ws;
  ushort* x_b      = (ushort*)(ws);                        // 8 MB
  ushort* hl_b     = (ushort*)(ws + 8388608);              // 8 MB
  ushort* pooled_b = (ushort*)(ws + 16777216);             // 8 MB
  ushort* hmem_b   = (ushort*)(ws + 25165824);             // 8 MB
  ushort* WspT     = (ushort*)(ws + 33554432);             // 128 KB
  ushort* WcatT    = (ushort*)(ws + 33685504);             // 1.5 MB
  ushort* gates    = (ushort*)(ws + 35258368);             // 32 MB

  prep_weights<<<3328, 256, 0, stream>>>(W_sp, W_ih, W_hh, WspT, WcatT);

  event_pool<<<B_SZ / 4, 256, 0, stream>>>(
      x_t, h_lstm, slots, ptr, W_val, b_val, W_ev, b_ev, pos_emb, slot_w,
      out_slots, out_ptr, x_b, hl_b, pooled_b);

  // h_mem = pooled @ W_sp + b_sp   (M=16384, N=256, K=256)
  gemm_bf16<256, 256, 0><<<dim3(128, 2), 256, 0, stream>>>(
      pooled_b, pooled_b, pooled_b, WspT, b_sp, out_hmem, hmem_b);

  // gates = [x | h_mem | h_lstm] @ [W_ih; W_hh] + b_ih   (M=16384, N=1024, K=768)
  gemm_bf16<768, 1024, 1><<<dim3(128, 8), 256, 0, stream>>>(
      x_b, hmem_b, hl_b, WcatT, b_ih, nullptr, gates);

  lstm_ew<<<B_SZ * 64 / 256, 256, 0, stream>>>(gates, c_lstm, out_h, out_c);
}

// Round 2
// 304.938 us; speedup vs baseline: 1.0133x; 1.0133x over previous
//
#include <hip/hip_runtime.h>
#include <hip/hip_bf16.h>

#define B_SZ 16384
#define I_SZ 256
#define H_SZ 256
#define S_SZ 32

typedef __attribute__((ext_vector_type(8))) short short8;
typedef __attribute__((ext_vector_type(4))) float f32x4;

__device__ __forceinline__ ushort f2b(float f) {
  __hip_bfloat16 h = __float2bfloat16(f);
  return *reinterpret_cast<ushort*>(&h);
}
__device__ __forceinline__ float sgm(float x) { return 1.0f / (1.0f + expf(-x)); }

__device__ __forceinline__ void gll16(const void* g, void* l) {
  __builtin_amdgcn_global_load_lds(
      (const __attribute__((address_space(1))) unsigned*)g,
      (__attribute__((address_space(3))) unsigned*)l, 16, 0, 0);
}

// ---------------- prep: convert + transpose weights to bf16 ----------------
// WspT[n][k] = W_sp[k][n]   (256 x 256)
// WcatT: gate-interleaved permuted rows of [W_ih; W_hh]^T (1024 x 768):
//   row r -> (hb=r>>6, g=(r>>4)&3, hl=r&15), n = g*256 + hb*16 + hl
//   WcatT[r][k] = k<512 ? W_ih[k][n] : W_hh[k-512][n]
__global__ __launch_bounds__(256) void prep_weights(
    const float* __restrict__ W_sp, const float* __restrict__ W_ih,
    const float* __restrict__ W_hh, ushort* __restrict__ WspT,
    ushort* __restrict__ WcatT) {
  int idx = blockIdx.x * 256 + threadIdx.x;
  if (idx < 256 * 256) {
    int n = idx >> 8, k = idx & 255;
    WspT[idx] = f2b(W_sp[k * 256 + n]);
  } else {
    int j = idx - 256 * 256;  // < 1024*768
    int r = j / 768, k = j - r * 768;
    int hb = r >> 6, g = (r >> 4) & 3, hl = r & 15;
    int n = g * 256 + hb * 16 + hl;
    float v = (k < 512) ? W_ih[k * 1024 + n] : W_hh[(k - 512) * 1024 + n];
    WcatT[j] = f2b(v);
  }
}

// ---------------- fused event gate + scatter-copy + pooled ----------------
// One wave per batch row. 256 threads = 4 rows/block.
__global__ __launch_bounds__(256) void event_pool(
    const float* __restrict__ x_t, const float* __restrict__ h_lstm,
    const float* __restrict__ slots, const int* __restrict__ ptr,
    const float* __restrict__ W_val, const float* __restrict__ b_val,
    const float* __restrict__ W_ev, const float* __restrict__ b_ev,
    const float* __restrict__ pos_emb, const float* __restrict__ slot_w,
    float* __restrict__ out_slots, float* __restrict__ out_ptr,
    ushort* __restrict__ x_b, ushort* __restrict__ hl_b,
    ushort* __restrict__ pooled_b) {
  int l = threadIdx.x & 63;
  int w = threadIdx.x >> 6;
  int b = blockIdx.x * 4 + w;
  __shared__ float x_sh[4][256];

  float4 x4 = *(const float4*)(x_t + (size_t)b * 256 + l * 4);
  *(float4*)&x_sh[w][l * 4] = x4;
  ushort4 xb = make_ushort4(f2b(x4.x), f2b(x4.y), f2b(x4.z), f2b(x4.w));
  *(ushort4*)&x_b[(size_t)b * 256 + l * 4] = xb;
  float4 hl4 = *(const float4*)(h_lstm + (size_t)b * 256 + l * 4);
  ushort4 hb = make_ushort4(f2b(hl4.x), f2b(hl4.y), f2b(hl4.z), f2b(hl4.w));
  *(ushort4*)&hl_b[(size_t)b * 256 + l * 4] = hb;

  // event gate: z = dot(x, W_ev) + b_ev  (fp32, wave butterfly reduce)
  float4 we4 = *(const float4*)(W_ev + l * 4);
  float p = x4.x * we4.x + x4.y * we4.y + x4.z * we4.z + x4.w * we4.w;
  for (int off = 32; off; off >>= 1) p += __shfl_xor(p, off, 64);
  float z = p + b_ev[0];
  bool ev = sgm(z) > 0.85f;
  int pb = ptr[b];

  __syncthreads();  // x_sh ready

  // v = x @ W_val + b_val  (fp32) — only when the (rare) event fires
  float4 v4 = make_float4(0.f, 0.f, 0.f, 0.f);
  if (ev) {
    v4 = *(const float4*)(b_val + l * 4);
    for (int k = 0; k < 256; k++) {
      float xv = x_sh[w][k];
      float4 wv = *(const float4*)(W_val + (size_t)k * 256 + l * 4);
      v4.x += xv * wv.x; v4.y += xv * wv.y;
      v4.z += xv * wv.z; v4.w += xv * wv.w;
    }
  }

  // softmax(slot_weights) — tiny, computed redundantly per lane
  float mx = -1e30f;
  for (int s = 0; s < 32; s++) mx = fmaxf(mx, slot_w[s]);
  float sum = 0.f;
  for (int s = 0; s < 32; s++) sum += expf(slot_w[s] - mx);
  float rs = 1.f / sum;

  // single pass: copy slots -> out (with scatter), accumulate pooled
  const float4* sl4 = (const float4*)slots + (size_t)b * 2048;
  float4* os4 = (float4*)out_slots + (size_t)b * 2048;
  const float4* pe4 = (const float4*)pos_emb;
  float4 pool = make_float4(0.f, 0.f, 0.f, 0.f);
#pragma unroll 8
  for (int s = 0; s < 32; s++) {
    float ws_ = expf(slot_w[s] - mx) * rs;
    float4 t = sl4[s * 64 + l];
    if (ev && s == pb) t = v4;
    os4[s * 64 + l] = t;
    float4 pe = pe4[s * 64 + l];
    pool.x += ws_ * (t.x + pe.x);
    pool.y += ws_ * (t.y + pe.y);
    pool.z += ws_ * (t.z + pe.z);
    pool.w += ws_ * (t.w + pe.w);
  }
  ushort4 pb4 = make_ushort4(f2b(pool.x), f2b(pool.y), f2b(pool.z), f2b(pool.w));
  *(ushort4*)&pooled_b[(size_t)b * 256 + l * 4] = pb4;

  if (l == 0) out_ptr[b] = (float)(ev ? ((pb + 1) & 31) : pb);
}

// ---------------- bf16 MFMA GEMM: C = A(MxK) * W^T(NxK) + bias ----------------
// A split over up to 3 row-major (x,256) bf16 sources along K (256 each).
// EPI 0: write fp32 out + bf16 copy (h_mem).
// EPI 2: fused LSTM elementwise epilogue (gate-interleaved WT rows; the four
//        N-fragments n=0..3 of a wave are the four gates i,f,g,o of the SAME
//        16 hidden units, so each lane holds i/f/g/o for one (row,h) in-reg).
template <int KTOT, int NTOT, int EPI>
__global__ __launch_bounds__(256) void gemm_bf16(
    const ushort* __restrict__ A0, const ushort* __restrict__ A1,
    const ushort* __restrict__ A2, const ushort* __restrict__ WT,
    const float* __restrict__ bias, float* __restrict__ out_f32,
    ushort* __restrict__ out_b16, const float* __restrict__ c_lstm,
    float* __restrict__ h_out, float* __restrict__ c_out) {
  int l = threadIdx.x & 63;
  int wid = threadIdx.x >> 6;
  int wm = wid >> 1, wn = wid & 1;
  int m0 = blockIdx.x * 128;
  int n0 = blockIdx.y * 128;
  __shared__ ushort Ash[128 * 32];
  __shared__ ushort Bsh[128 * 32];

  f32x4 acc[4][4] = {};

  for (int k0 = 0; k0 < KTOT; k0 += 32) {
    const ushort* As = (k0 < 256) ? A0 : ((k0 < 512) ? A1 : A2);
    int kc = k0 & 255;
#pragma unroll
    for (int i = 0; i < 2; i++) {
      int seg = i * 256 + threadIdx.x;
      int row = seg >> 2, cb = (seg & 3) * 8;
      gll16(As + (size_t)(m0 + row) * 256 + kc + cb, Ash + seg * 8);
    }
#pragma unroll
    for (int i = 0; i < 2; i++) {
      int seg = i * 256 + threadIdx.x;
      int row = seg >> 2, cb = (seg & 3) * 8;
      gll16(WT + (size_t)(n0 + row) * KTOT + k0 + cb, Bsh + seg * 8);
    }
    __syncthreads();

    short8 af[4], bfr[4];
#pragma unroll
    for (int m = 0; m < 4; m++)
      af[m] = *(const short8*)&Ash[(wm * 64 + m * 16 + (l & 15)) * 32 + (l >> 4) * 8];
#pragma unroll
    for (int n = 0; n < 4; n++)
      bfr[n] = *(const short8*)&Bsh[(wn * 64 + n * 16 + (l & 15)) * 32 + (l >> 4) * 8];
#pragma unroll
    for (int m = 0; m < 4; m++)
#pragma unroll
      for (int n = 0; n < 4; n++)
        acc[m][n] = __builtin_amdgcn_mfma_f32_16x16x32_bf16(af[m], bfr[n], acc[m][n], 0, 0, 0);
    __syncthreads();
  }

  if constexpr (EPI == 0) {
#pragma unroll
    for (int m = 0; m < 4; m++)
#pragma unroll
      for (int n = 0; n < 4; n++)
#pragma unroll
        for (int r = 0; r < 4; r++) {
          int row = m0 + wm * 64 + m * 16 + (l >> 4) * 4 + r;
          int col = n0 + wn * 64 + n * 16 + (l & 15);
          float v = acc[m][n][r] + bias[col];
          out_f32[(size_t)row * NTOT + col] = v;
          out_b16[(size_t)row * NTOT + col] = f2b(v);
        }
  } else {
    // fused LSTM: h = ((n0>>6)+wn)*16 + (l&15); gate = n-fragment index
    int h = ((n0 >> 6) + wn) * 16 + (l & 15);
    float bi = bias[h], bf_ = bias[256 + h], bg = bias[512 + h], bo = bias[768 + h];
#pragma unroll
    for (int m = 0; m < 4; m++)
#pragma unroll
      for (int r = 0; r < 4; r++) {
        int row = m0 + wm * 64 + m * 16 + (l >> 4) * 4 + r;
        float ig = acc[m][0][r] + bi;
        float fg = acc[m][1][r] + bf_;
        float gt = acc[m][2][r] + bg;
        float og = acc[m][3][r] + bo;
        float c = c_lstm[(size_t)row * 256 + h];
        float cn = sgm(fg) * c + sgm(ig) * tanhf(gt);
        float hn = sgm(og) * tanhf(cn);
        c_out[(size_t)row * 256 + h] = cn;
        h_out[(size_t)row * 256 + h] = hn;
      }
  }
}

extern "C" void kernel_launch(void* const* d_in, const int* in_sizes, int n_in,
                              void* d_out, int out_size, void* d_ws, size_t ws_size,
                              hipStream_t stream) {
  const float* x_t    = (const float*)d_in[0];
  const float* h_lstm = (const float*)d_in[1];
  const float* c_lstm = (const float*)d_in[2];
  // d_in[3] = h_mem_prev (unused by reference)
  const float* slots  = (const float*)d_in[4];
  const int*   ptr    = (const int*)d_in[5];
  const float* W_val  = (const float*)d_in[6];
  const float* b_val  = (const float*)d_in[7];
  const float* W_ev   = (const float*)d_in[8];
  const float* b_ev   = (const float*)d_in[9];
  const float* pos_emb = (const float*)d_in[10];
  const float* slot_w  = (const float*)d_in[11];
  const float* W_sp   = (const float*)d_in[12];
  const float* b_sp   = (const float*)d_in[13];
  const float* W_ih   = (const float*)d_in[14];
  const float* b_ih   = (const float*)d_in[15];
  const float* W_hh   = (const float*)d_in[16];

  float* out = (float*)d_out;
  const size_t BH = (size_t)B_SZ * H_SZ;              // 4,194,304
  float* out_h    = out;
  float* out_c    = out + BH;
  float* out_hmem = out + 2 * BH;
  float* out_slots = out + 3 * BH;
  float* out_ptr   = out + 3 * BH + (size_t)B_SZ * S_SZ * I_SZ;

  char* ws = (char*)d_ws;
  ushort* x_b      = (ushort*)(ws);                        // 8 MB
  ushort* hl_b     = (ushort*)(ws + 8388608);              // 8 MB
  ushort* pooled_b = (ushort*)(ws + 16777216);             // 8 MB
  ushort* hmem_b   = (ushort*)(ws + 25165824);             // 8 MB
  ushort* WspT     = (ushort*)(ws + 33554432);             // 128 KB
  ushort* WcatT    = (ushort*)(ws + 33685504);             // 1.5 MB

  prep_weights<<<3328, 256, 0, stream>>>(W_sp, W_ih, W_hh, WspT, WcatT);

  event_pool<<<B_SZ / 4, 256, 0, stream>>>(
      x_t, h_lstm, slots, ptr, W_val, b_val, W_ev, b_ev, pos_emb, slot_w,
      out_slots, out_ptr, x_b, hl_b, pooled_b);

  // h_mem = pooled @ W_sp + b_sp   (M=16384, N=256, K=256)
  gemm_bf16<256, 256, 0><<<dim3(128, 2), 256, 0, stream>>>(
      pooled_b, pooled_b, pooled_b, WspT, b_sp, out_hmem, hmem_b,
      nullptr, nullptr, nullptr);

  // gates = [x | h_mem | h_lstm] @ perm([W_ih; W_hh]) + b_ih, fused LSTM
  // (M=16384, N=1024, K=768)
  gemm_bf16<768, 1024, 2><<<dim3(128, 8), 256, 0, stream>>>(
      x_b, hmem_b, hl_b, WcatT, b_ih, nullptr, nullptr,
      c_lstm, out_h, out_c);
}

// Round 3
// 288.412 us; speedup vs baseline: 1.0714x; 1.0573x over previous
//
#include <hip/hip_runtime.h>
#include <hip/hip_bf16.h>

#define B_SZ 16384
#define I_SZ 256
#define H_SZ 256
#define S_SZ 32

typedef __attribute__((ext_vector_type(8))) short short8;
typedef __attribute__((ext_vector_type(4))) float f32x4;

__device__ __forceinline__ ushort f2b(float f) {
  __hip_bfloat16 h = __float2bfloat16(f);
  return *reinterpret_cast<ushort*>(&h);
}
__device__ __forceinline__ float sgm(float x) { return 1.0f / (1.0f + expf(-x)); }

__device__ __forceinline__ void gll16(const void* g, void* l) {
  __builtin_amdgcn_global_load_lds(
      (const __attribute__((address_space(1))) unsigned*)g,
      (__attribute__((address_space(3))) unsigned*)l, 16, 0, 0);
}

// ---------------- prep: convert + transpose weights to bf16 ----------------
__global__ __launch_bounds__(256) void prep_weights(
    const float* __restrict__ W_sp, const float* __restrict__ W_ih,
    const float* __restrict__ W_hh, ushort* __restrict__ WspT,
    ushort* __restrict__ WcatT) {
  int idx = blockIdx.x * 256 + threadIdx.x;
  if (idx < 256 * 256) {
    int n = idx >> 8, k = idx & 255;
    WspT[idx] = f2b(W_sp[k * 256 + n]);
  } else {
    int j = idx - 256 * 256;  // < 1024*768
    int r = j / 768, k = j - r * 768;
    int hb = r >> 6, g = (r >> 4) & 3, hl = r & 15;
    int n = g * 256 + hb * 16 + hl;
    float v = (k < 512) ? W_ih[k * 1024 + n] : W_hh[(k - 512) * 1024 + n];
    WcatT[j] = f2b(v);
  }
}

// ---------------- fused event gate + scatter-copy + pooled ----------------
__global__ __launch_bounds__(256) void event_pool(
    const float* __restrict__ x_t, const float* __restrict__ h_lstm,
    const float* __restrict__ slots, const int* __restrict__ ptr,
    const float* __restrict__ W_val, const float* __restrict__ b_val,
    const float* __restrict__ W_ev, const float* __restrict__ b_ev,
    const float* __restrict__ pos_emb, const float* __restrict__ slot_w,
    float* __restrict__ out_slots, float* __restrict__ out_ptr,
    ushort* __restrict__ x_b, ushort* __restrict__ hl_b,
    ushort* __restrict__ pooled_b) {
  int l = threadIdx.x & 63;
  int w = threadIdx.x >> 6;
  int b = blockIdx.x * 4 + w;
  __shared__ float x_sh[4][256];

  float4 x4 = *(const float4*)(x_t + (size_t)b * 256 + l * 4);
  *(float4*)&x_sh[w][l * 4] = x4;
  ushort4 xb = make_ushort4(f2b(x4.x), f2b(x4.y), f2b(x4.z), f2b(x4.w));
  *(ushort4*)&x_b[(size_t)b * 256 + l * 4] = xb;
  float4 hl4 = *(const float4*)(h_lstm + (size_t)b * 256 + l * 4);
  ushort4 hb = make_ushort4(f2b(hl4.x), f2b(hl4.y), f2b(hl4.z), f2b(hl4.w));
  *(ushort4*)&hl_b[(size_t)b * 256 + l * 4] = hb;

  float4 we4 = *(const float4*)(W_ev + l * 4);
  float p = x4.x * we4.x + x4.y * we4.y + x4.z * we4.z + x4.w * we4.w;
  for (int off = 32; off; off >>= 1) p += __shfl_xor(p, off, 64);
  float z = p + b_ev[0];
  bool ev = sgm(z) > 0.85f;
  int pb = ptr[b];

  __syncthreads();

  float4 v4 = make_float4(0.f, 0.f, 0.f, 0.f);
  if (ev) {
    v4 = *(const float4*)(b_val + l * 4);
    for (int k = 0; k < 256; k++) {
      float xv = x_sh[w][k];
      float4 wv = *(const float4*)(W_val + (size_t)k * 256 + l * 4);
      v4.x += xv * wv.x; v4.y += xv * wv.y;
      v4.z += xv * wv.z; v4.w += xv * wv.w;
    }
  }

  float mx = -1e30f;
  for (int s = 0; s < 32; s++) mx = fmaxf(mx, slot_w[s]);
  float sum = 0.f;
  for (int s = 0; s < 32; s++) sum += expf(slot_w[s] - mx);
  float rs = 1.f / sum;

  const float4* sl4 = (const float4*)slots + (size_t)b * 2048;
  float4* os4 = (float4*)out_slots + (size_t)b * 2048;
  const float4* pe4 = (const float4*)pos_emb;
  float4 pool = make_float4(0.f, 0.f, 0.f, 0.f);
#pragma unroll 8
  for (int s = 0; s < 32; s++) {
    float ws_ = expf(slot_w[s] - mx) * rs;
    float4 t = sl4[s * 64 + l];
    if (ev && s == pb) t = v4;
    os4[s * 64 + l] = t;
    float4 pe = pe4[s * 64 + l];
    pool.x += ws_ * (t.x + pe.x);
    pool.y += ws_ * (t.y + pe.y);
    pool.z += ws_ * (t.z + pe.z);
    pool.w += ws_ * (t.w + pe.w);
  }
  ushort4 pb4 = make_ushort4(f2b(pool.x), f2b(pool.y), f2b(pool.z), f2b(pool.w));
  *(ushort4*)&pooled_b[(size_t)b * 256 + l * 4] = pb4;

  if (l == 0) out_ptr[b] = (float)(ev ? ((pb + 1) & 31) : pb);
}

// ---------------- small GEMM (h_mem): 128^2 tile, fp32 + bf16 out ----------
__global__ __launch_bounds__(256) void gemm_hmem(
    const ushort* __restrict__ A0, const ushort* __restrict__ WT,
    const float* __restrict__ bias, float* __restrict__ out_f32,
    ushort* __restrict__ out_b16) {
  int l = threadIdx.x & 63;
  int wid = threadIdx.x >> 6;
  int wm = wid >> 1, wn = wid & 1;
  int m0 = blockIdx.x * 128;
  int n0 = blockIdx.y * 128;
  __shared__ ushort Ash[128 * 32];
  __shared__ ushort Bsh[128 * 32];

  f32x4 acc[4][4] = {};

  for (int k0 = 0; k0 < 256; k0 += 32) {
#pragma unroll
    for (int i = 0; i < 2; i++) {
      int seg = i * 256 + threadIdx.x;
      int row = seg >> 2, cb = (seg & 3) * 8;
      gll16(A0 + (size_t)(m0 + row) * 256 + k0 + cb, Ash + seg * 8);
    }
#pragma unroll
    for (int i = 0; i < 2; i++) {
      int seg = i * 256 + threadIdx.x;
      int row = seg >> 2, cb = (seg & 3) * 8;
      gll16(WT + (size_t)(n0 + row) * 256 + k0 + cb, Bsh + seg * 8);
    }
    __syncthreads();

    short8 af[4], bfr[4];
#pragma unroll
    for (int m = 0; m < 4; m++)
      af[m] = *(const short8*)&Ash[(wm * 64 + m * 16 + (l & 15)) * 32 + (l >> 4) * 8];
#pragma unroll
    for (int n = 0; n < 4; n++)
      bfr[n] = *(const short8*)&Bsh[(wn * 64 + n * 16 + (l & 15)) * 32 + (l >> 4) * 8];
#pragma unroll
    for (int m = 0; m < 4; m++)
#pragma unroll
      for (int n = 0; n < 4; n++)
        acc[m][n] = __builtin_amdgcn_mfma_f32_16x16x32_bf16(af[m], bfr[n], acc[m][n], 0, 0, 0);
    __syncthreads();
  }

#pragma unroll
  for (int m = 0; m < 4; m++)
#pragma unroll
    for (int n = 0; n < 4; n++)
#pragma unroll
      for (int r = 0; r < 4; r++) {
        int row = m0 + wm * 64 + m * 16 + (l >> 4) * 4 + r;
        int col = n0 + wn * 64 + n * 16 + (l & 15);
        float v = acc[m][n][r] + bias[col];
        out_f32[(size_t)row * 256 + col] = v;
        out_b16[(size_t)row * 256 + col] = f2b(v);
      }
}

// ------- gates GEMM, 256x256 tile, BK=64, 4-phase counted-vmcnt pipeline ----
// A = [x | h_mem | h_lstm] (3 x row-major 256-wide bf16), B = WcatT (1024x768,
// gate-interleaved rows). Fused LSTM epilogue. Read-side XOR chunk swizzle
// (C ^= row&7) realized via pre-swizzled GLOBAL source addrs (LDS stays linear).
template <int KTOT>
__global__ __launch_bounds__(512) void gemm256_lstm(
    const ushort* __restrict__ A0s, const ushort* __restrict__ A1s,
    const ushort* __restrict__ A2s, const ushort* __restrict__ WT,
    const float* __restrict__ bias, const float* __restrict__ c_lstm,
    float* __restrict__ h_out, float* __restrict__ c_out) {
  constexpr int NT = KTOT / 64;  // 12
  __shared__ ushort Ash[2][2][128][64];  // [buf][half][row][col] 64 KiB
  __shared__ ushort Bsh[2][2][128][64];  // 64 KiB
  const int tid = threadIdx.x;
  const int l = tid & 63;
  const int wid = tid >> 6;
  const int wm = wid >> 2, wn = wid & 3;
  const int id = blockIdx.x;
  const int xcd = id & 7, jj = id >> 3;
  const int mb = xcd * 8 + (jj >> 2), nb = jj & 3;
  const int m0 = mb * 256, n0 = nb * 256;

  auto asel = [&](int kt) { return kt < 4 ? A0s : (kt < 8 ? A1s : A2s); };

  auto stageA = [&](int bu, int h, int kt) {
    const ushort* s = asel(kt);
    int cb = (kt & 3) * 64;
#pragma unroll
    for (int ld = 0; ld < 2; ld++) {
      int seg = ld * 512 + tid;
      int row = seg >> 3, C = seg & 7;
      int Cs = C ^ (row & 7);
      gll16(s + (size_t)(m0 + h * 128 + row) * 256 + cb + Cs * 8,
            &Ash[bu][h][0][0] + seg * 8);
    }
  };
  auto stageB = [&](int bu, int h, int kt) {
    int cb = kt * 64;
#pragma unroll
    for (int ld = 0; ld < 2; ld++) {
      int seg = ld * 512 + tid;
      int row = seg >> 3, C = seg & 7;
      int Cs = C ^ (row & 7);
      gll16(WT + (size_t)(n0 + h * 128 + row) * KTOT + cb + Cs * 8,
            &Bsh[bu][h][0][0] + seg * 8);
    }
  };

  f32x4 acc[8][4] = {};

  // prologue: t0.{B0,B1,A0,A1}, t1.{B0,B1}  (6 half-tiles, 12 loads)
  stageB(0, 0, 0); stageB(0, 1, 0);
  stageA(0, 0, 0); stageA(0, 1, 0);
  stageB(1, 0, 1); stageB(1, 1, 1);

  for (int t = 0; t < NT; t++) {
    const int c = t & 1;
    const ushort* Abase = &Ash[c][wm][0][0];
    const ushort* Bbase = &Bsh[c][wn >> 1][0][0];

    // ---- phase 0 ----
    if (t < NT - 1) asm volatile("s_waitcnt vmcnt(4)" ::: "memory");
    else            asm volatile("s_waitcnt vmcnt(0)" ::: "memory");
    asm volatile("s_barrier" ::: "memory");

    short8 bfr[4][2];
#pragma unroll
    for (int nf = 0; nf < 4; nf++)
#pragma unroll
      for (int kk = 0; kk < 2; kk++) {
        int r = (wn & 1) * 64 + nf * 16 + (l & 15);
        int C = (kk * 4 + (l >> 4)) ^ (l & 7);
        bfr[nf][kk] = *(const short8*)(Bbase + r * 64 + C * 8);
      }
    short8 af[2][2];
#pragma unroll
    for (int q = 0; q < 2; q++)
#pragma unroll
      for (int kk = 0; kk < 2; kk++) {
        int r = (0 * 2 + q) * 16 + (l & 15);
        int C = (kk * 4 + (l >> 4)) ^ (l & 7);
        af[q][kk] = *(const short8*)(Abase + r * 64 + C * 8);
      }
    if (t + 1 < NT) stageA(c ^ 1, 0, t + 1);
    __builtin_amdgcn_s_setprio(1);
#pragma unroll
    for (int q = 0; q < 2; q++)
#pragma unroll
      for (int nf = 0; nf < 4; nf++)
#pragma unroll
        for (int kk = 0; kk < 2; kk++)
          acc[q][nf] = __builtin_amdgcn_mfma_f32_16x16x32_bf16(
              af[q][kk], bfr[nf][kk], acc[q][nf], 0, 0, 0);
    __builtin_amdgcn_s_setprio(0);

    // ---- phases 1..3 ----
#pragma unroll
    for (int p = 1; p < 4; p++) {
      asm volatile("s_barrier" ::: "memory");
#pragma unroll
      for (int q = 0; q < 2; q++)
#pragma unroll
        for (int kk = 0; kk < 2; kk++) {
          int r = (p * 2 + q) * 16 + (l & 15);
          int C = (kk * 4 + (l >> 4)) ^ (l & 7);
          af[q][kk] = *(const short8*)(Abase + r * 64 + C * 8);
        }
      if (p == 1) {
        if (t + 1 < NT) stageA(c ^ 1, 1, t + 1);
        if (t + 2 < NT) stageB(c, 0, t + 2);
      } else if (p == 2) {
        if (t + 2 < NT) stageB(c, 1, t + 2);
      }
      __builtin_amdgcn_s_setprio(1);
#pragma unroll
      for (int q = 0; q < 2; q++)
#pragma unroll
        for (int nf = 0; nf < 4; nf++)
#pragma unroll
          for (int kk = 0; kk < 2; kk++)
            acc[p * 2 + q][nf] = __builtin_amdgcn_mfma_f32_16x16x32_bf16(
                af[q][kk], bfr[nf][kk], acc[p * 2 + q][nf], 0, 0, 0);
      __builtin_amdgcn_s_setprio(0);
    }
  }

  // ---- fused LSTM epilogue ----
  // col n_abs = n0 + wn*64 + nf*16 + (l&15) -> gate nf of hidden unit
  // h = (nb*4 + wn)*16 + (l&15)
  int h = (nb * 4 + wn) * 16 + (l & 15);
  float bi = bias[h], bf_ = bias[256 + h], bg = bias[512 + h], bo = bias[768 + h];
#pragma unroll
  for (int mf = 0; mf < 8; mf++)
#pragma unroll
    for (int r = 0; r < 4; r++) {
      int row = m0 + wm * 128 + mf * 16 + (l >> 4) * 4 + r;
      float ig = acc[mf][0][r] + bi;
      float fg = acc[mf][1][r] + bf_;
      float gt = acc[mf][2][r] + bg;
      float og = acc[mf][3][r] + bo;
      float cc = c_lstm[(size_t)row * 256 + h];
      float cn = sgm(fg) * cc + sgm(ig) * tanhf(gt);
      float hn = sgm(og) * tanhf(cn);
      c_out[(size_t)row * 256 + h] = cn;
      h_out[(size_t)row * 256 + h] = hn;
    }
}

extern "C" void kernel_launch(void* const* d_in, const int* in_sizes, int n_in,
                              void* d_out, int out_size, void* d_ws, size_t ws_size,
                              hipStream_t stream) {
  const float* x_t    = (const float*)d_in[0];
  const float* h_lstm = (const float*)d_in[1];
  const float* c_lstm = (const float*)d_in[2];
  const float* slots  = (const float*)d_in[4];
  const int*   ptr    = (const int*)d_in[5];
  const float* W_val  = (const float*)d_in[6];
  const float* b_val  = (const float*)d_in[7];
  const float* W_ev   = (const float*)d_in[8];
  const float* b_ev   = (const float*)d_in[9];
  const float* pos_emb = (const float*)d_in[10];
  const float* slot_w  = (const float*)d_in[11];
  const float* W_sp   = (const float*)d_in[12];
  const float* b_sp   = (const float*)d_in[13];
  const float* W_ih   = (const float*)d_in[14];
  const float* b_ih   = (const float*)d_in[15];
  const float* W_hh   = (const float*)d_in[16];

  float* out = (float*)d_out;
  const size_t BH = (size_t)B_SZ * H_SZ;
  float* out_h    = out;
  float* out_c    = out + BH;
  float* out_hmem = out + 2 * BH;
  float* out_slots = out + 3 * BH;
  float* out_ptr   = out + 3 * BH + (size_t)B_SZ * S_SZ * I_SZ;

  char* ws = (char*)d_ws;
  ushort* x_b      = (ushort*)(ws);                        // 8 MB
  ushort* hl_b     = (ushort*)(ws + 8388608);              // 8 MB
  ushort* pooled_b = (ushort*)(ws + 16777216);             // 8 MB
  ushort* hmem_b   = (ushort*)(ws + 25165824);             // 8 MB
  ushort* WspT     = (ushort*)(ws + 33554432);             // 128 KB
  ushort* WcatT    = (ushort*)(ws + 33685504);             // 1.5 MB

  prep_weights<<<3328, 256, 0, stream>>>(W_sp, W_ih, W_hh, WspT, WcatT);

  event_pool<<<B_SZ / 4, 256, 0, stream>>>(
      x_t, h_lstm, slots, ptr, W_val, b_val, W_ev, b_ev, pos_emb, slot_w,
      out_slots, out_ptr, x_b, hl_b, pooled_b);

  // h_mem = pooled @ W_sp + b_sp   (M=16384, N=256, K=256)
  gemm_hmem<<<dim3(128, 2), 256, 0, stream>>>(
      pooled_b, WspT, b_sp, out_hmem, hmem_b);

  // gates = [x | h_mem | h_lstm] @ perm([W_ih; W_hh]) + b_ih, fused LSTM
  gemm256_lstm<768><<<256, 512, 0, stream>>>(
      x_b, hmem_b, hl_b, WcatT, b_ih, c_lstm, out_h, out_c);
}

// Round 4
// 249.340 us; speedup vs baseline: 1.2393x; 1.1567x over previous
//
#include <hip/hip_runtime.h>
#include <hip/hip_bf16.h>

#define B_SZ 16384
#define I_SZ 256
#define H_SZ 256
#define S_SZ 32

typedef __attribute__((ext_vector_type(8))) short short8;
typedef __attribute__((ext_vector_type(4))) float f32x4;

__device__ __forceinline__ ushort f2b(float f) {
  __hip_bfloat16 h = __float2bfloat16(f);
  return *reinterpret_cast<ushort*>(&h);
}
__device__ __forceinline__ float sgm(float x) { return 1.0f / (1.0f + expf(-x)); }

__device__ __forceinline__ void gll16(const void* g, void* l) {
  __builtin_amdgcn_global_load_lds(
      (const __attribute__((address_space(1))) unsigned*)g,
      (__attribute__((address_space(3))) unsigned*)l, 16, 0, 0);
}

// ============ front kernel: event_pool + all weight prep (block-role split) ==
// blocks [0,4096)        : event/scatter/pool (4 rows each)
// blocks [4096,4104)     : WspT convert-transpose (256x256)
// blocks [4104,4168)     : WcatT k<256 (x part) and k>=512 (h_lstm part)
// blocks [4168,4424)     : Weff = W_sp @ W2 -> bf16 into WcatT k in [256,512)
// block  4424            : bias' = b_ih + b_sp @ W2
__global__ __launch_bounds__(256) void front(
    const float* __restrict__ x_t, const float* __restrict__ h_lstm,
    const float* __restrict__ slots, const int* __restrict__ ptr,
    const float* __restrict__ W_val, const float* __restrict__ b_val,
    const float* __restrict__ W_ev, const float* __restrict__ b_ev,
    const float* __restrict__ pos_emb, const float* __restrict__ slot_w,
    const float* __restrict__ W_sp, const float* __restrict__ W_ih,
    const float* __restrict__ W_hh, const float* __restrict__ b_ih,
    const float* __restrict__ b_sp,
    float* __restrict__ out_slots, float* __restrict__ out_ptr,
    ushort* __restrict__ x_b, ushort* __restrict__ hl_b,
    ushort* __restrict__ pooled_b, ushort* __restrict__ WspT,
    ushort* __restrict__ WcatT, float* __restrict__ biasp) {
  __shared__ float x_sh[4][256];
  const int bid = blockIdx.x;
  const int t = threadIdx.x;

  if (bid < 4096) {
    // ---------------- event / scatter-copy / pool ----------------
    int l = t & 63;
    int w = t >> 6;
    int b = bid * 4 + w;

    float4 x4 = *(const float4*)(x_t + (size_t)b * 256 + l * 4);
    *(float4*)&x_sh[w][l * 4] = x4;
    ushort4 xb = make_ushort4(f2b(x4.x), f2b(x4.y), f2b(x4.z), f2b(x4.w));
    *(ushort4*)&x_b[(size_t)b * 256 + l * 4] = xb;
    float4 hl4 = *(const float4*)(h_lstm + (size_t)b * 256 + l * 4);
    ushort4 hb = make_ushort4(f2b(hl4.x), f2b(hl4.y), f2b(hl4.z), f2b(hl4.w));
    *(ushort4*)&hl_b[(size_t)b * 256 + l * 4] = hb;

    float4 we4 = *(const float4*)(W_ev + l * 4);
    float p = x4.x * we4.x + x4.y * we4.y + x4.z * we4.z + x4.w * we4.w;
    for (int off = 32; off; off >>= 1) p += __shfl_xor(p, off, 64);
    float z = p + b_ev[0];
    bool ev = sgm(z) > 0.85f;
    int pb = ptr[b];

    __syncthreads();

    f32x4 v4 = {0.f, 0.f, 0.f, 0.f};
    if (ev) {
      v4 = *(const f32x4*)(b_val + l * 4);
      for (int k = 0; k < 256; k++) {
        float xv = x_sh[w][k];
        f32x4 wv = *(const f32x4*)(W_val + (size_t)k * 256 + l * 4);
        v4 += xv * wv;
      }
    }

    float mx = -1e30f;
    for (int s = 0; s < 32; s++) mx = fmaxf(mx, slot_w[s]);
    float sum = 0.f;
    for (int s = 0; s < 32; s++) sum += expf(slot_w[s] - mx);
    float rs = 1.f / sum;

    const f32x4* sl4 = (const f32x4*)slots + (size_t)b * 2048;
    f32x4* os4 = (f32x4*)out_slots + (size_t)b * 2048;
    const f32x4* pe4 = (const f32x4*)pos_emb;
    f32x4 pool = {0.f, 0.f, 0.f, 0.f};
#pragma unroll 8
    for (int s = 0; s < 32; s++) {
      float ws_ = expf(slot_w[s] - mx) * rs;
      f32x4 tv = __builtin_nontemporal_load(sl4 + s * 64 + l);
      if (ev && s == pb) tv = v4;
      __builtin_nontemporal_store(tv, os4 + s * 64 + l);
      f32x4 pe = pe4[s * 64 + l];
      pool += ws_ * (tv + pe);
    }
    ushort4 pb4 = make_ushort4(f2b(pool[0]), f2b(pool[1]), f2b(pool[2]), f2b(pool[3]));
    *(ushort4*)&pooled_b[(size_t)b * 256 + l * 4] = pb4;

    if (l == 0) out_ptr[b] = (float)(ev ? ((pb + 1) & 31) : pb);

  } else if (bid < 4104) {
    // ---------------- WspT[n][k] = bf16(W_sp[k][n]) ----------------
    for (int e = (bid - 4096) * 256 + t; e < 65536; e += 8 * 256) {
      int n = e >> 8, k = e & 255;
      WspT[e] = f2b(W_sp[k * 256 + n]);
    }
  } else if (bid < 4168) {
    // -------- WcatT rows, k<256 (from W_ih x-part) and k>=512 (W_hh) -------
    for (int e = (bid - 4104) * 256 + t; e < 1024 * 512; e += 64 * 256) {
      int r = e >> 9, kk = e & 511;
      int k = (kk < 256) ? kk : kk + 256;
      int hb = r >> 6, g = (r >> 4) & 3, hl = r & 15;
      int n = g * 256 + hb * 16 + hl;
      float v = (k < 512) ? W_ih[(size_t)k * 1024 + n]
                          : W_hh[(size_t)(k - 512) * 1024 + n];
      WcatT[(size_t)r * 768 + k] = f2b(v);
    }
  } else if (bid < 4424) {
    // -------- Weff[i][n] = sum_m W_sp[i][m] * W_ih[256+m][n]  (fp32) -------
    int i = bid - 4168;
    x_sh[0][t] = W_sp[(size_t)i * 256 + t];
    __syncthreads();
    int n0 = t * 4;
    f32x4 acc = {0.f, 0.f, 0.f, 0.f};
    for (int m = 0; m < 256; m++) {
      float s = x_sh[0][m];
      f32x4 w2 = *(const f32x4*)(W_ih + (size_t)(256 + m) * 1024 + n0);
      acc += s * w2;
    }
#pragma unroll
    for (int d = 0; d < 4; d++) {
      int n = n0 + d;
      int g = n >> 8, rem = n & 255, hb = rem >> 4, hl = rem & 15;
      int r = hb * 64 + g * 16 + hl;
      WcatT[(size_t)r * 768 + 256 + i] = f2b(acc[d]);
    }
  } else {
    // -------- bias'[n] = b_ih[n] + sum_m b_sp[m] * W_ih[256+m][n] ---------
    int n0 = t * 4;
    f32x4 acc = *(const f32x4*)(b_ih + n0);
    for (int m = 0; m < 256; m++) {
      float s = b_sp[m];
      f32x4 w2 = *(const f32x4*)(W_ih + (size_t)(256 + m) * 1024 + n0);
      acc += s * w2;
    }
    *(f32x4*)(biasp + n0) = acc;
  }
}

// ---------------- h_mem output GEMM (fp32 out only): 128^2 tile -------------
__global__ __launch_bounds__(256) void gemm_hmem(
    const ushort* __restrict__ A0, const ushort* __restrict__ WT,
    const float* __restrict__ bias, float* __restrict__ out_f32) {
  int l = threadIdx.x & 63;
  int wid = threadIdx.x >> 6;
  int wm = wid >> 1, wn = wid & 1;
  int m0 = blockIdx.x * 128;
  int n0 = blockIdx.y * 128;
  __shared__ ushort Ash[128 * 32];
  __shared__ ushort Bsh[128 * 32];

  f32x4 acc[4][4] = {};

  for (int k0 = 0; k0 < 256; k0 += 32) {
#pragma unroll
    for (int i = 0; i < 2; i++) {
      int seg = i * 256 + threadIdx.x;
      int row = seg >> 2, cb = (seg & 3) * 8;
      gll16(A0 + (size_t)(m0 + row) * 256 + k0 + cb, Ash + seg * 8);
    }
#pragma unroll
    for (int i = 0; i < 2; i++) {
      int seg = i * 256 + threadIdx.x;
      int row = seg >> 2, cb = (seg & 3) * 8;
      gll16(WT + (size_t)(n0 + row) * 256 + k0 + cb, Bsh + seg * 8);
    }
    __syncthreads();

    short8 af[4], bfr[4];
#pragma unroll
    for (int m = 0; m < 4; m++)
      af[m] = *(const short8*)&Ash[(wm * 64 + m * 16 + (l & 15)) * 32 + (l >> 4) * 8];
#pragma unroll
    for (int n = 0; n < 4; n++)
      bfr[n] = *(const short8*)&Bsh[(wn * 64 + n * 16 + (l & 15)) * 32 + (l >> 4) * 8];
#pragma unroll
    for (int m = 0; m < 4; m++)
#pragma unroll
      for (int n = 0; n < 4; n++)
        acc[m][n] = __builtin_amdgcn_mfma_f32_16x16x32_bf16(af[m], bfr[n], acc[m][n], 0, 0, 0);
    __syncthreads();
  }

#pragma unroll
  for (int m = 0; m < 4; m++)
#pragma unroll
    for (int n = 0; n < 4; n++)
#pragma unroll
      for (int r = 0; r < 4; r++) {
        int row = m0 + wm * 64 + m * 16 + (l >> 4) * 4 + r;
        int col = n0 + wn * 64 + n * 16 + (l & 15);
        out_f32[(size_t)row * 256 + col] = acc[m][n][r] + bias[col];
      }
}

// ------- gates GEMM, 256x256 tile, BK=64, 4-phase counted-vmcnt pipeline ----
// A = [x | pooled | h_lstm], B = WcatT (x | Weff | h_lstm segments,
// gate-interleaved rows). Fused LSTM epilogue.
template <int KTOT>
__global__ __launch_bounds__(512) void gemm256_lstm(
    const ushort* __restrict__ A0s, const ushort* __restrict__ A1s,
    const ushort* __restrict__ A2s, const ushort* __restrict__ WT,
    const float* __restrict__ bias, const float* __restrict__ c_lstm,
    float* __restrict__ h_out, float* __restrict__ c_out) {
  constexpr int NT = KTOT / 64;  // 12
  __shared__ ushort Ash[2][2][128][64];
  __shared__ ushort Bsh[2][2][128][64];
  const int tid = threadIdx.x;
  const int l = tid & 63;
  const int wid = tid >> 6;
  const int wm = wid >> 2, wn = wid & 3;
  const int id = blockIdx.x;
  const int xcd = id & 7, jj = id >> 3;
  const int mb = xcd * 8 + (jj >> 2), nb = jj & 3;
  const int m0 = mb * 256, n0 = nb * 256;

  auto asel = [&](int kt) { return kt < 4 ? A0s : (kt < 8 ? A1s : A2s); };

  auto stageA = [&](int bu, int h, int kt) {
    const ushort* s = asel(kt);
    int cb = (kt & 3) * 64;
#pragma unroll
    for (int ld = 0; ld < 2; ld++) {
      int seg = ld * 512 + tid;
      int row = seg >> 3, C = seg & 7;
      int Cs = C ^ (row & 7);
      gll16(s + (size_t)(m0 + h * 128 + row) * 256 + cb + Cs * 8,
            &Ash[bu][h][0][0] + seg * 8);
    }
  };
  auto stageB = [&](int bu, int h, int kt) {
    int cb = kt * 64;
#pragma unroll
    for (int ld = 0; ld < 2; ld++) {
      int seg = ld * 512 + tid;
      int row = seg >> 3, C = seg & 7;
      int Cs = C ^ (row & 7);
      gll16(WT + (size_t)(n0 + h * 128 + row) * KTOT + cb + Cs * 8,
            &Bsh[bu][h][0][0] + seg * 8);
    }
  };

  f32x4 acc[8][4] = {};

  stageB(0, 0, 0); stageB(0, 1, 0);
  stageA(0, 0, 0); stageA(0, 1, 0);
  stageB(1, 0, 1); stageB(1, 1, 1);

  for (int t = 0; t < NT; t++) {
    const int c = t & 1;
    const ushort* Abase = &Ash[c][wm][0][0];
    const ushort* Bbase = &Bsh[c][wn >> 1][0][0];

    if (t < NT - 1) asm volatile("s_waitcnt vmcnt(4)" ::: "memory");
    else            asm volatile("s_waitcnt vmcnt(0)" ::: "memory");
    asm volatile("s_barrier" ::: "memory");

    short8 bfr[4][2];
#pragma unroll
    for (int nf = 0; nf < 4; nf++)
#pragma unroll
      for (int kk = 0; kk < 2; kk++) {
        int r = (wn & 1) * 64 + nf * 16 + (l & 15);
        int C = (kk * 4 + (l >> 4)) ^ (l & 7);
        bfr[nf][kk] = *(const short8*)(Bbase + r * 64 + C * 8);
      }
    short8 af[2][2];
#pragma unroll
    for (int q = 0; q < 2; q++)
#pragma unroll
      for (int kk = 0; kk < 2; kk++) {
        int r = (0 * 2 + q) * 16 + (l & 15);
        int C = (kk * 4 + (l >> 4)) ^ (l & 7);
        af[q][kk] = *(const short8*)(Abase + r * 64 + C * 8);
      }
    if (t + 1 < NT) stageA(c ^ 1, 0, t + 1);
    __builtin_amdgcn_s_setprio(1);
#pragma unroll
    for (int q = 0; q < 2; q++)
#pragma unroll
      for (int nf = 0; nf < 4; nf++)
#pragma unroll
        for (int kk = 0; kk < 2; kk++)
          acc[q][nf] = __builtin_amdgcn_mfma_f32_16x16x32_bf16(
              af[q][kk], bfr[nf][kk], acc[q][nf], 0, 0, 0);
    __builtin_amdgcn_s_setprio(0);

#pragma unroll
    for (int p = 1; p < 4; p++) {
      asm volatile("s_barrier" ::: "memory");
#pragma unroll
      for (int q = 0; q < 2; q++)
#pragma unroll
        for (int kk = 0; kk < 2; kk++) {
          int r = (p * 2 + q) * 16 + (l & 15);
          int C = (kk * 4 + (l >> 4)) ^ (l & 7);
          af[q][kk] = *(const short8*)(Abase + r * 64 + C * 8);
        }
      if (p == 1) {
        if (t + 1 < NT) stageA(c ^ 1, 1, t + 1);
        if (t + 2 < NT) stageB(c, 0, t + 2);
      } else if (p == 2) {
        if (t + 2 < NT) stageB(c, 1, t + 2);
      }
      __builtin_amdgcn_s_setprio(1);
#pragma unroll
      for (int q = 0; q < 2; q++)
#pragma unroll
        for (int nf = 0; nf < 4; nf++)
#pragma unroll
          for (int kk = 0; kk < 2; kk++)
            acc[p * 2 + q][nf] = __builtin_amdgcn_mfma_f32_16x16x32_bf16(
                af[q][kk], bfr[nf][kk], acc[p * 2 + q][nf], 0, 0, 0);
      __builtin_amdgcn_s_setprio(0);
    }
  }

  int h = (nb * 4 + wn) * 16 + (l & 15);
  float bi = bias[h], bf_ = bias[256 + h], bg = bias[512 + h], bo = bias[768 + h];
#pragma unroll
  for (int mf = 0; mf < 8; mf++)
#pragma unroll
    for (int r = 0; r < 4; r++) {
      int row = m0 + wm * 128 + mf * 16 + (l >> 4) * 4 + r;
      float ig = acc[mf][0][r] + bi;
      float fg = acc[mf][1][r] + bf_;
      float gt = acc[mf][2][r] + bg;
      float og = acc[mf][3][r] + bo;
      float cc = c_lstm[(size_t)row * 256 + h];
      float cn = sgm(fg) * cc + sgm(ig) * tanhf(gt);
      float hn = sgm(og) * tanhf(cn);
      c_out[(size_t)row * 256 + h] = cn;
      h_out[(size_t)row * 256 + h] = hn;
    }
}

extern "C" void kernel_launch(void* const* d_in, const int* in_sizes, int n_in,
                              void* d_out, int out_size, void* d_ws, size_t ws_size,
                              hipStream_t stream) {
  const float* x_t    = (const float*)d_in[0];
  const float* h_lstm = (const float*)d_in[1];
  const float* c_lstm = (const float*)d_in[2];
  const float* slots  = (const float*)d_in[4];
  const int*   ptr    = (const int*)d_in[5];
  const float* W_val  = (const float*)d_in[6];
  const float* b_val  = (const float*)d_in[7];
  const float* W_ev   = (const float*)d_in[8];
  const float* b_ev   = (const float*)d_in[9];
  const float* pos_emb = (const float*)d_in[10];
  const float* slot_w  = (const float*)d_in[11];
  const float* W_sp   = (const float*)d_in[12];
  const float* b_sp   = (const float*)d_in[13];
  const float* W_ih   = (const float*)d_in[14];
  const float* b_ih   = (const float*)d_in[15];
  const float* W_hh   = (const float*)d_in[16];

  float* out = (float*)d_out;
  const size_t BH = (size_t)B_SZ * H_SZ;
  float* out_h    = out;
  float* out_c    = out + BH;
  float* out_hmem = out + 2 * BH;
  float* out_slots = out + 3 * BH;
  float* out_ptr   = out + 3 * BH + (size_t)B_SZ * S_SZ * I_SZ;

  char* ws = (char*)d_ws;
  ushort* x_b      = (ushort*)(ws);                        // 8 MB
  ushort* hl_b     = (ushort*)(ws + 8388608);              // 8 MB
  ushort* pooled_b = (ushort*)(ws + 16777216);             // 8 MB
  ushort* WspT     = (ushort*)(ws + 25165824);             // 128 KB
  ushort* WcatT    = (ushort*)(ws + 25296896);             // 1.5 MB
  float*  biasp    = (float*)(ws + 26869760);              // 4 KB

  front<<<4425, 256, 0, stream>>>(
      x_t, h_lstm, slots, ptr, W_val, b_val, W_ev, b_ev, pos_emb, slot_w,
      W_sp, W_ih, W_hh, b_ih, b_sp,
      out_slots, out_ptr, x_b, hl_b, pooled_b, WspT, WcatT, biasp);

  // gates = [x | pooled | h_lstm] @ WcatT + bias', fused LSTM
  gemm256_lstm<768><<<256, 512, 0, stream>>>(
      x_b, pooled_b, hl_b, WcatT, biasp, c_lstm, out_h, out_c);

  // h_mem = pooled @ W_sp + b_sp  (fp32 output only)
  gemm_hmem<<<dim3(128, 2), 256, 0, stream>>>(
      pooled_b, WspT, b_sp, out_hmem);
}